// Round 1
// baseline (764.969 us; speedup 1.0000x reference)
//
#include <hip/hip_runtime.h>

#define PLANE 262144  // 512*512

// ---------------- Kernel 1: global average pool (partial sums + atomic) ---------
__global__ __launch_bounds__(256) void pool_kernel(const float* __restrict__ x,
                                                   float* __restrict__ pooled) {
    // 2048 blocks: 8 blocks per (b,c) plane. Each block sums 32768 floats.
    int bc   = blockIdx.x >> 3;
    int part = blockIdx.x & 7;
    const float4* p = (const float4*)(x + (size_t)bc * PLANE) + part * 8192;
    int t = threadIdx.x;
    float s = 0.f;
    #pragma unroll 8
    for (int it = 0; it < 32; ++it) {
        float4 v = p[it * 256 + t];
        s += (v.x + v.y) + (v.z + v.w);
    }
    #pragma unroll
    for (int off = 32; off > 0; off >>= 1) s += __shfl_down(s, off, 64);
    __shared__ float partial[4];
    if ((t & 63) == 0) partial[t >> 6] = s;
    __syncthreads();
    if (t == 0) atomicAdd(&pooled[bc], (partial[0] + partial[1]) + (partial[2] + partial[3]));
}

// ---------------- Kernel 2: routing softmax + expert kernel mixing --------------
// wmix layout: [b][i][o][12] floats (k = kh*3+kw in slots 0..8, slots 9..11 zero)
__global__ __launch_bounds__(256) void route_mix_kernel(
    const float* __restrict__ pooled, const float* __restrict__ w_experts,
    const float* __restrict__ fc_w, const float* __restrict__ fc_b,
    float* __restrict__ wmix) {
    int b = blockIdx.x;
    float l[3];
    #pragma unroll
    for (int e = 0; e < 3; ++e) {
        float acc = fc_b[e];
        #pragma unroll
        for (int c = 0; c < 16; ++c)
            acc += (pooled[b * 16 + c] * (1.f / 262144.f)) * fc_w[e * 16 + c];
        l[e] = acc;
    }
    float mx = fmaxf(fmaxf(l[0], l[1]), l[2]);
    float r0 = expf(l[0] - mx), r1 = expf(l[1] - mx), r2 = expf(l[2] - mx);
    float inv = 1.f / (r0 + r1 + r2);
    r0 *= inv; r1 *= inv; r2 *= inv;

    int t = threadIdx.x;          // 256 threads <-> 256 (i,o) pairs
    int i = t >> 4, o = t & 15;
    // w_experts layout: [e][o][i][3][3] -> ((e*16+o)*16+i)*9 + k
    int base = (o * 16 + i) * 9;
    float* wout = wmix + ((size_t)(b * 16 + i) * 16 + o) * 12;
    #pragma unroll
    for (int k = 0; k < 9; ++k) {
        float v = r0 * w_experts[base + k]
                + r1 * w_experts[base + 2304 + k]
                + r2 * w_experts[base + 4608 + k];
        wout[k] = v;
    }
    wout[9] = 0.f; wout[10] = 0.f; wout[11] = 0.f;
}

// ---------------- Kernel 3: per-sample 3x3 conv, reflect pad 1 ------------------
// Thread: 4 vertical pixels x all 16 output channels. Block: 64 cols x 16 rows.
__global__ __launch_bounds__(256) void conv_kernel(
    const float* __restrict__ x, const float* __restrict__ wmix,
    const float* __restrict__ bias, float* __restrict__ out) {
    const int b  = blockIdx.z;
    const int tx = threadIdx.x & 63;
    const int ty = threadIdx.x >> 6;
    const int col = blockIdx.x * 64 + tx;
    const int r0  = blockIdx.y * 16 + ty * 4;

    // Reflected offsets for 6 rows x 3 cols (pad=1 reflect: -1 -> 1, 512 -> 510)
    int off[6][3];
    #pragma unroll
    for (int rr = 0; rr < 6; ++rr) {
        int r = r0 - 1 + rr;
        r = (r < 0) ? 1 : ((r > 511) ? 510 : r);
        #pragma unroll
        for (int cc = 0; cc < 3; ++cc) {
            int c = col - 1 + cc;
            c = (c < 0) ? 1 : ((c > 511) ? 510 : c);
            off[rr][cc] = r * 512 + c;
        }
    }

    float acc[4][16];
    #pragma unroll
    for (int p = 0; p < 4; ++p)
        #pragma unroll
        for (int o = 0; o < 16; ++o) acc[p][o] = 0.f;

    const float* xb = x + (size_t)b * 16 * PLANE;
    // weights: uniform indices -> compiler emits s_load -> SGPR operands in FMA
    const float4* wb = (const float4*)wmix + (size_t)b * 768;  // [i][o][3] float4

    #pragma unroll 1
    for (int i = 0; i < 16; ++i) {
        float xv[6][3];
        #pragma unroll
        for (int rr = 0; rr < 6; ++rr)
            #pragma unroll
            for (int cc = 0; cc < 3; ++cc)
                xv[rr][cc] = xb[off[rr][cc]];

        #pragma unroll
        for (int o = 0; o < 16; ++o) {
            float4 w0 = wb[(i * 16 + o) * 3 + 0];
            float4 w1 = wb[(i * 16 + o) * 3 + 1];
            float4 w2 = wb[(i * 16 + o) * 3 + 2];
            #pragma unroll
            for (int p = 0; p < 4; ++p) {
                float s = xv[p    ][0] * w0.x + xv[p    ][1] * w0.y + xv[p    ][2] * w0.z
                        + xv[p + 1][0] * w0.w + xv[p + 1][1] * w1.x + xv[p + 1][2] * w1.y
                        + xv[p + 2][0] * w1.z + xv[p + 2][1] * w1.w + xv[p + 2][2] * w2.x;
                acc[p][o] += s;
            }
        }
        xb += PLANE;
    }

    #pragma unroll
    for (int o = 0; o < 16; ++o) {
        float bo = bias[o];
        float* op = out + (((size_t)(b * 16 + o)) * 512 + r0) * 512 + col;
        #pragma unroll
        for (int p = 0; p < 4; ++p)
            op[p * 512] = acc[p][o] + bo;
    }
}

extern "C" void kernel_launch(void* const* d_in, const int* in_sizes, int n_in,
                              void* d_out, int out_size, void* d_ws, size_t ws_size,
                              hipStream_t stream) {
    const float* x         = (const float*)d_in[0];
    const float* w_experts = (const float*)d_in[1];
    const float* bias      = (const float*)d_in[2];
    const float* fc_w      = (const float*)d_in[3];
    const float* fc_b      = (const float*)d_in[4];
    float* out = (float*)d_out;

    float* pooled = (float*)d_ws;          // 256 floats
    float* wmix   = pooled + 256;          // 16*16*16*12 = 49152 floats (16B-aligned)

    hipMemsetAsync(pooled, 0, 256 * sizeof(float), stream);
    pool_kernel<<<2048, 256, 0, stream>>>(x, pooled);
    route_mix_kernel<<<16, 256, 0, stream>>>(pooled, w_experts, fc_w, fc_b, wmix);
    conv_kernel<<<dim3(8, 32, 16), 256, 0, stream>>>(x, wmix, bias, out);
}

// Round 2
// 538.899 us; speedup vs baseline: 1.4195x; 1.4195x over previous
//
#include <hip/hip_runtime.h>

#define PLANE 262144  // 512*512

typedef __attribute__((ext_vector_type(8))) short bf16x8;
typedef __attribute__((ext_vector_type(4))) float f32x4;

__device__ inline short f2bf(float f) {
    union { float f; unsigned u; } v; v.f = f;
    unsigned r = (v.u + 0x7FFFu + ((v.u >> 16) & 1u)) >> 16;  // RNE
    return (short)r;
}

// ---------------- Kernel 1: global average pool (partial sums + atomic) ---------
__global__ __launch_bounds__(256) void pool_kernel(const float* __restrict__ x,
                                                   float* __restrict__ pooled) {
    int bc   = blockIdx.x >> 3;
    int part = blockIdx.x & 7;
    const float4* p = (const float4*)(x + (size_t)bc * PLANE) + part * 8192;
    int t = threadIdx.x;
    float s = 0.f;
    #pragma unroll 8
    for (int it = 0; it < 32; ++it) {
        float4 v = p[it * 256 + t];
        s += (v.x + v.y) + (v.z + v.w);
    }
    #pragma unroll
    for (int off = 32; off > 0; off >>= 1) s += __shfl_down(s, off, 64);
    __shared__ float partial[4];
    if ((t & 63) == 0) partial[t >> 6] = s;
    __syncthreads();
    if (t == 0) atomicAdd(&pooled[bc], (partial[0] + partial[1]) + (partial[2] + partial[3]));
}

// ---------------- Kernel 2: routing softmax + A-fragment-ordered weight mix -----
// wA layout: [b][t][lane][j] bf16 — exactly the MFMA A-fragment order.
// k = tap*16 + c, tap-major; lane: o=lane&15, q=lane>>4; k=(q*8+j)+32t
//   => tap = 2t + (q>>1), c = (q&1)*8 + j.  tap 9 (pad) = zero weights.
__global__ __launch_bounds__(320) void route_mix_kernel(
    const float* __restrict__ pooled, const float* __restrict__ w_experts,
    const float* __restrict__ fc_w, const float* __restrict__ fc_b,
    bf16x8* __restrict__ wA) {
    int b = blockIdx.x;
    float l0 = fc_b[0], l1 = fc_b[1], l2 = fc_b[2];
    #pragma unroll
    for (int c = 0; c < 16; ++c) {
        float pc = pooled[b * 16 + c] * (1.f / 262144.f);
        l0 += pc * fc_w[c]; l1 += pc * fc_w[16 + c]; l2 += pc * fc_w[32 + c];
    }
    float mx = fmaxf(fmaxf(l0, l1), l2);
    float r0 = expf(l0 - mx), r1 = expf(l1 - mx), r2 = expf(l2 - mx);
    float inv = 1.f / (r0 + r1 + r2);
    r0 *= inv; r1 *= inv; r2 *= inv;

    int item = threadIdx.x;            // 320 = 5 t-slots * 64 lanes
    int t = item >> 6, l = item & 63;
    int o = l & 15, q = l >> 4;
    int tap = 2 * t + (q >> 1);
    int c0 = (q & 1) * 8;
    bf16x8 vals;
    #pragma unroll
    for (int j = 0; j < 8; ++j) {
        float v = 0.f;
        if (tap < 9) {
            int c = c0 + j;
            int base = (o * 16 + c) * 9 + tap;   // [e][o][i][kh*3+kw]
            v = r0 * w_experts[base] + r1 * w_experts[2304 + base]
              + r2 * w_experts[4608 + base];
        }
        vals[j] = f2bf(v);
    }
    wA[(b * 5 + t) * 64 + l] = vals;
}

// ---------------- Kernel 3: MFMA conv, implicit GEMM over K = 10 taps x 16 ch ---
// Block: one sample, 16-row x 64-col output tile. LDS: 18x68 pixels x 16ch bf16.
__global__ __launch_bounds__(256) void conv_kernel(
    const float* __restrict__ x, const bf16x8* __restrict__ wA,
    const float* __restrict__ bias, float* __restrict__ out) {
    __shared__ int4 lds4[18 * 68 * 2];           // 39168 B
    char* ldsb = (char*)lds4;
    const int b = blockIdx.z;
    const int row0 = blockIdx.y * 16, col0 = blockIdx.x * 64;
    const int tid = threadIdx.x;
    const float* xb = x + (size_t)b * 16 * PLANE;

    // ---- stage tile (18 rows x 68 cols, 16 ch) fp32 -> bf16, [pix][ch] layout
    #pragma unroll
    for (int k = 0; k < 5; ++k) {
        int pos = tid + k * 256;
        if (pos < 18 * 68) {
            int rr = pos / 68, cp = pos - rr * 68;
            int gr = row0 + rr - 1; gr = gr < 0 ? 1 : (gr > 511 ? 1022 - gr : gr);
            int gc = col0 + cp - 1; gc = gc < 0 ? 1 : (gc > 511 ? 1022 - gc : gc);
            const float* px = xb + gr * 512 + gc;
            #pragma unroll
            for (int half = 0; half < 2; ++half) {
                bf16x8 pk;
                #pragma unroll
                for (int j = 0; j < 8; ++j)
                    pk[j] = f2bf(px[(size_t)(half * 8 + j) * PLANE]);
                *(bf16x8*)(ldsb + pos * 32 + half * 16) = pk;
            }
        }
    }

    // ---- A fragments (5 MFMAs worth, preformatted by route_mix)
    const int lane = tid & 63, wv = tid >> 6;
    bf16x8 af[5];
    #pragma unroll
    for (int t = 0; t < 5; ++t) af[t] = wA[(b * 5 + t) * 64 + lane];

    // ---- per-lane B-fragment byte offsets for each MFMA t
    const int q = lane >> 4, p = lane & 15, h = q >> 1;
    int offt[5];
    #pragma unroll
    for (int t = 0; t < 5; ++t) {
        int tap = 2 * t + h; if (tap > 8) tap = 8;   // tap 9: A is zero, read tap8
        int kh = tap / 3, kw = tap - kh * 3;
        offt[t] = (kh * 68 + kw + p) * 32 + (q & 1) * 16;
    }

    float4 bq = ((const float4*)bias)[q];            // bias for o = q*4 + reg
    float bb[4] = {bq.x, bq.y, bq.z, bq.w};

    __syncthreads();

    #pragma unroll 1
    for (int r = 0; r < 4; ++r) {
        const int R = wv * 4 + r;                    // local output row
        const char* baseR = ldsb + R * 2176;         // 68*32 bytes per row
        f32x4 a0 = {0.f,0.f,0.f,0.f}, a1 = a0, a2 = a0, a3 = a0;
        #pragma unroll
        for (int t = 0; t < 5; ++t) {
            bf16x8 b0 = *(const bf16x8*)(baseR +        offt[t]);
            bf16x8 b1 = *(const bf16x8*)(baseR +  512 + offt[t]);
            bf16x8 b2 = *(const bf16x8*)(baseR + 1024 + offt[t]);
            bf16x8 b3 = *(const bf16x8*)(baseR + 1536 + offt[t]);
            a0 = __builtin_amdgcn_mfma_f32_16x16x32_bf16(af[t], b0, a0, 0, 0, 0);
            a1 = __builtin_amdgcn_mfma_f32_16x16x32_bf16(af[t], b1, a1, 0, 0, 0);
            a2 = __builtin_amdgcn_mfma_f32_16x16x32_bf16(af[t], b2, a2, 0, 0, 0);
            a3 = __builtin_amdgcn_mfma_f32_16x16x32_bf16(af[t], b3, a3, 0, 0, 0);
        }
        // C/D: col = lane&15 (pixel), row = q*4 + reg (output channel)
        size_t obase = ((size_t)(b * 16 + q * 4) * 512 + (row0 + R)) * 512 + col0 + p;
        #pragma unroll
        for (int reg = 0; reg < 4; ++reg) {
            float* op = out + obase + (size_t)reg * PLANE;
            op[0]  = a0[reg] + bb[reg];
            op[16] = a1[reg] + bb[reg];
            op[32] = a2[reg] + bb[reg];
            op[48] = a3[reg] + bb[reg];
        }
    }
}

extern "C" void kernel_launch(void* const* d_in, const int* in_sizes, int n_in,
                              void* d_out, int out_size, void* d_ws, size_t ws_size,
                              hipStream_t stream) {
    const float* x         = (const float*)d_in[0];
    const float* w_experts = (const float*)d_in[1];
    const float* bias      = (const float*)d_in[2];
    const float* fc_w      = (const float*)d_in[3];
    const float* fc_b      = (const float*)d_in[4];
    float* out = (float*)d_out;

    float*  pooled = (float*)d_ws;                       // 256 floats
    bf16x8* wA     = (bf16x8*)((char*)d_ws + 1024);      // 16*5*64 vecs = 80 KiB

    hipMemsetAsync(pooled, 0, 256 * sizeof(float), stream);
    pool_kernel<<<2048, 256, 0, stream>>>(x, pooled);
    route_mix_kernel<<<16, 320, 0, stream>>>(pooled, w_experts, fc_w, fc_b, wA);
    conv_kernel<<<dim3(8, 32, 16), 256, 0, stream>>>(x, wA, bias, out);
}